// Round 8
// baseline (1893.904 us; speedup 1.0000x reference)
//
#include <hip/hip_runtime.h>

#define HD 64
#define L2E 1.4426950408889634f

typedef _Float16 v2h __attribute__((ext_vector_type(2)));

__device__ __forceinline__ float fexp2(float x) { return __builtin_amdgcn_exp2f(x); }
__device__ __forceinline__ float frcp(float x)  { return __builtin_amdgcn_rcpf(x); }
__device__ __forceinline__ float ftanh_fast(float x) {
    return 1.f - 2.f * frcp(fexp2(2.f * L2E * x) + 1.f);
}

__device__ __forceinline__ float FDOT2(v2h a, v2h b, float c) {
    return __builtin_amdgcn_fdot2(a, b, c, false);
}
__device__ __forceinline__ v2h RLPAIR(int bits, int k) {
    return __builtin_bit_cast(v2h, __builtin_amdgcn_readlane(bits, k));
}

// One workgroup (512 threads = 8 waves) per batch element.
// Quad-gate layout: lane l -> gate g=l&3, unit u=16*(wave&3)+(l>>2), row=g*64+u.
// A (waves 0-3): f16 rows of Whh0 AND Wih1 (64 VGPRs). One h0(i-1) pair-read
//   serves both the layer-0 dot (t=i) and the xproj dot (t=i-1) — the fold.
// C (waves 4-7): f16 row of Whh1; layer-1 recurrence t=i-2; output head t=i-2.
// KEY: dots consume h via ONE ds_read_b32 (lane l&31 holds f16-pair l&31) +
// unrolled v_readlane -> SGPR + v_dot2_f32_f16. DS-pipe instruction count per
// iteration drops ~8x vs broadcast ds_read_b128 (R7's measured bottleneck).
// ONE barrier/iter; parity double buffers, deps >=1 iter apart; all LDS
// zero-initialized pre-loop (launch-history independence, per R6 lesson).
__launch_bounds__(512, 2)
__global__ void lstm2_kernel(const float* __restrict__ x,     // [B,T]
                             const float* __restrict__ h0in,  // [2,B,HD]
                             const float* __restrict__ c0in,  // [2,B,HD]
                             const float* __restrict__ Wih0,  // [4H,1]
                             const float* __restrict__ Whh0,  // [4H,HD]
                             const float* __restrict__ bih0,
                             const float* __restrict__ bhh0,
                             const float* __restrict__ Wih1,  // [4H,HD]
                             const float* __restrict__ Whh1,  // [4H,HD]
                             const float* __restrict__ bih1,
                             const float* __restrict__ bhh1,
                             const float* __restrict__ Wlin,  // [1,HD]
                             const float* __restrict__ blin,  // [1]
                             float* __restrict__ out,         // [B,T]
                             int B, int T)
{
    const int b    = blockIdx.x;
    const int tid  = threadIdx.x;
    const int wave = tid >> 6;
    const int lane = tid & 63;
    const int gg   = lane & 3;                      // gate: 0=i 1=f 2=g 3=o
    const int j    = (wave & 3) * 16 + (lane >> 2); // hidden unit
    const int row  = gg * HD + j;
    const bool isA = (wave < 4);

    __shared__ __align__(4) _Float16 h0buf[2][HD];
    __shared__ __align__(4) _Float16 h1buf[2][HD];
    __shared__ float xbuf[2][4][80];     // [parity][gate][unit], stride 80: 2-way free
    __shared__ __align__(16) float opart[2][4];

    // ---- zero-init ALL LDS (launch-history independence) ----
    if (tid < 128) { h0buf[tid >> 6][tid & 63] = (_Float16)0.f;
                     h1buf[tid >> 6][tid & 63] = (_Float16)0.f; }
    { float* xb = &xbuf[0][0][0];
      for (int idx = tid; idx < 2 * 4 * 80; idx += 512) xb[idx] = 0.f; }
    if (tid < 8) opart[tid >> 2][tid & 3] = 0.f;

    v2h w0[32];                          // A: Whh0 row | C: Whh1 row
    v2h w1[32];                          // A: Wih1 row | C: unused
    float base0 = 0.f, bias1 = 0.f, wx0 = 0.f, cst = 0.f, wl = 0.f;

    // branchless activation: act = c1 + c2 * rcp(exp2(aa*x) + 1)
    const float aa = (gg == 2) ? 2.f * L2E : -L2E;
    const float c1 = (gg == 2) ? 1.f : 0.f;
    const float c2 = (gg == 2) ? -2.f : 1.f;

    if (isA) {
        const float4* wp = (const float4*)(Whh0 + row * HD);
        const float4* up = (const float4*)(Wih1 + row * HD);
        #pragma unroll
        for (int q = 0; q < 16; ++q) {
            float4 v = wp[q];
            w0[2*q]   = v2h{(_Float16)v.x, (_Float16)v.y};
            w0[2*q+1] = v2h{(_Float16)v.z, (_Float16)v.w};
            float4 t = up[q];
            w1[2*q]   = v2h{(_Float16)t.x, (_Float16)t.y};
            w1[2*q+1] = v2h{(_Float16)t.z, (_Float16)t.w};
        }
        base0 = bih0[row] + bhh0[row];
        wx0   = Wih0[row];
        bias1 = bih1[row] + bhh1[row];
        if (gg == 0) cst = c0in[b * HD + j];
        if (tid < HD) h0buf[1][tid] = (_Float16)h0in[b * HD + tid];
    } else {
        const float4* wp = (const float4*)(Whh1 + row * HD);
        #pragma unroll
        for (int q = 0; q < 16; ++q) {
            float4 v = wp[q];
            w0[2*q]   = v2h{(_Float16)v.x, (_Float16)v.y};
            w0[2*q+1] = v2h{(_Float16)v.z, (_Float16)v.w};
        }
        if (gg == 0) cst = c0in[B * HD + b * HD + j];
        wl = Wlin[j];
        if (tid >= 256 && tid < 256 + HD)
            h1buf[1][tid - 256] = (_Float16)h0in[B * HD + b * HD + (tid - 256)];
    }

    const float blin0 = blin[0];
    float xchunk = 0.f;
    const int pofs = lane & 31;          // this lane's f16-pair index

    for (int i = 0; i <= T + 2; ++i) {
        __syncthreads();

        if (isA) {
            if (i <= T) {
                if ((i & 63) == 0) {     // refill x cache (A waves only)
                    int idx = i + lane; if (idx >= T) idx = T - 1;
                    xchunk = x[b * T + idx];
                }
                // one ds_read_b32: lane (l&31) holds h0(i-1) pair (2p, 2p+1)
                int hbits = *(const int*)&h0buf[(i + 1) & 1][2 * pofs];
                float a0 = 0.f, a1 = 0.f, a2 = 0.f, a3 = 0.f;  // Whh0·h0
                float d0 = 0.f, d1 = 0.f, d2 = 0.f, d3 = 0.f;  // Wih1·h0
                #pragma unroll
                for (int k = 0; k < 32; k += 4) {
                    v2h p0 = RLPAIR(hbits, k);
                    v2h p1 = RLPAIR(hbits, k + 1);
                    v2h p2 = RLPAIR(hbits, k + 2);
                    v2h p3 = RLPAIR(hbits, k + 3);
                    a0 = FDOT2(w0[k],     p0, a0);
                    a1 = FDOT2(w0[k + 1], p1, a1);
                    a2 = FDOT2(w0[k + 2], p2, a2);
                    a3 = FDOT2(w0[k + 3], p3, a3);
                    d0 = FDOT2(w1[k],     p0, d0);
                    d1 = FDOT2(w1[k + 1], p1, d1);
                    d2 = FDOT2(w1[k + 2], p2, d2);
                    d3 = FDOT2(w1[k + 3], p3, d3);
                }
                if (i >= 1)              // xproj(t=i-1) = Wih1*h0(i-1) + biases
                    xbuf[(i + 1) & 1][gg][j] = bias1 + (d0 + d1) + (d2 + d3);
                if (i < T) {             // layer-0 gates + update, t = i
                    float xv  = __builtin_bit_cast(float,
                        __builtin_amdgcn_readlane(__builtin_bit_cast(int, xchunk), i & 63));
                    float pre = fmaf(wx0, xv, base0) + (a0 + a1) + (a2 + a3);
                    float act = fmaf(c2, frcp(fexp2(pre * aa) + 1.f), c1);
                    float v1 = __shfl_xor(act, 1, 64);
                    float v2 = __shfl_xor(act, 2, 64);
                    float v3 = __shfl_xor(act, 3, 64);
                    // gg==0 lanes: act=i, v1=f, v2=g, v3=o
                    cst = fmaf(v1, cst, act * v2);
                    float h = v3 * ftanh_fast(cst);
                    if (gg == 0) h0buf[i & 1][j] = (_Float16)h;
                }
            }
        } else {
            if (i >= 2 && i <= T + 1) {  // layer-1 recurrence + head, t = i-2
                int hbits = *(const int*)&h1buf[(i + 1) & 1][2 * pofs];
                float a0 = 0.f, a1 = 0.f, a2 = 0.f, a3 = 0.f;
                #pragma unroll
                for (int k = 0; k < 32; k += 4) {
                    a0 = FDOT2(w0[k],     RLPAIR(hbits, k),     a0);
                    a1 = FDOT2(w0[k + 1], RLPAIR(hbits, k + 1), a1);
                    a2 = FDOT2(w0[k + 2], RLPAIR(hbits, k + 2), a2);
                    a3 = FDOT2(w0[k + 3], RLPAIR(hbits, k + 3), a3);
                }
                float pre = xbuf[i & 1][gg][j] + (a0 + a1) + (a2 + a3);
                float act = fmaf(c2, frcp(fexp2(pre * aa) + 1.f), c1);
                float v1 = __shfl_xor(act, 1, 64);
                float v2 = __shfl_xor(act, 2, 64);
                float v3 = __shfl_xor(act, 3, 64);
                cst = fmaf(v1, cst, act * v2);
                float h = v3 * ftanh_fast(cst);
                if (gg == 0) h1buf[i & 1][j] = (_Float16)h;
                float p = (gg == 0) ? wl * h : 0.f;   // head partial, t = i-2
                p += __shfl_xor(p, 4, 64);
                p += __shfl_xor(p, 8, 64);
                p += __shfl_xor(p, 16, 64);
                p += __shfl_xor(p, 32, 64);
                if (lane == 0) opart[i & 1][wave & 3] = p;
            }
        }

        if (tid == 256 && i >= 3) {      // output store, t = i-3
            float4 op = *((const float4*)opart[(i + 1) & 1]);
            out[b * T + (i - 3)] = op.x + op.y + op.z + op.w + blin0;
        }
    }
}

extern "C" void kernel_launch(void* const* d_in, const int* in_sizes, int n_in,
                              void* d_out, int out_size, void* d_ws, size_t ws_size,
                              hipStream_t stream)
{
    const float* x    = (const float*)d_in[0];
    const float* h0   = (const float*)d_in[1];
    const float* c0   = (const float*)d_in[2];
    const float* Wih0 = (const float*)d_in[3];
    const float* Whh0 = (const float*)d_in[4];
    const float* bih0 = (const float*)d_in[5];
    const float* bhh0 = (const float*)d_in[6];
    const float* Wih1 = (const float*)d_in[7];
    const float* Whh1 = (const float*)d_in[8];
    const float* bih1 = (const float*)d_in[9];
    const float* bhh1 = (const float*)d_in[10];
    const float* Wlin = (const float*)d_in[11];
    const float* blin = (const float*)d_in[12];
    float* out = (float*)d_out;

    const int B = in_sizes[1] / (2 * HD);   // h0 is [2,B,HD]
    const int T = in_sizes[0] / B;          // input is [B,T]

    lstm2_kernel<<<dim3(B), dim3(512), 0, stream>>>(
        x, h0, c0, Wih0, Whh0, bih0, bhh0,
        Wih1, Whh1, bih1, bhh1, Wlin, blin, out, B, T);
}